// Round 3
// baseline (74.450 us; speedup 1.0000x reference)
//
#include <hip/hip_runtime.h>
#include <stdint.h>

// Problem constants (fixed by setup_inputs)
#define NB 8
#define NC 32
#define NK 36
#define NH 64
#define NW 64
// output plane per (b,c,k): 32x32 = 1024 floats = 256 float4 positions
// thread t in [0,256): oh = t>>3 (0..31), ow4 = t&7 (0..7; each covers 4 output cols)

// ---------------------------------------------------------------------------
// Pass 1: pack binary rfs into uint16 masks, one per (k, oh, ow4).
// bit j   (j=0..7)  = rfs[k][2*oh  ][8*ow4+j] > 0.5
// bit 8+j (j=0..7)  = rfs[k][2*oh+1][8*ow4+j] > 0.5
// ---------------------------------------------------------------------------
__global__ __launch_bounds__(256) void pack_masks(const float4* __restrict__ rfs4,
                                                  uint16_t* __restrict__ masks) {
    const int k = blockIdx.x;       // 0..35
    const int t = threadIdx.x;      // 0..255
    const int base = k * 1024 + (t >> 3) * 32 + (t & 7) * 2;  // float4 index
    float4 r0a = rfs4[base];        // row 2*oh,   cols 8*ow4+0..3
    float4 r0b = rfs4[base + 1];    // row 2*oh,   cols 8*ow4+4..7
    float4 r1a = rfs4[base + 16];   // row 2*oh+1, cols 8*ow4+0..3
    float4 r1b = rfs4[base + 17];   // row 2*oh+1, cols 8*ow4+4..7
    unsigned m = 0;
    m |= (unsigned)(r0a.x > 0.5f) << 0;
    m |= (unsigned)(r0a.y > 0.5f) << 1;
    m |= (unsigned)(r0a.z > 0.5f) << 2;
    m |= (unsigned)(r0a.w > 0.5f) << 3;
    m |= (unsigned)(r0b.x > 0.5f) << 4;
    m |= (unsigned)(r0b.y > 0.5f) << 5;
    m |= (unsigned)(r0b.z > 0.5f) << 6;
    m |= (unsigned)(r0b.w > 0.5f) << 7;
    m |= (unsigned)(r1a.x > 0.5f) << 8;
    m |= (unsigned)(r1a.y > 0.5f) << 9;
    m |= (unsigned)(r1a.z > 0.5f) << 10;
    m |= (unsigned)(r1a.w > 0.5f) << 11;
    m |= (unsigned)(r1b.x > 0.5f) << 12;
    m |= (unsigned)(r1b.y > 0.5f) << 13;
    m |= (unsigned)(r1b.z > 0.5f) << 14;
    m |= (unsigned)(r1b.w > 0.5f) << 15;
    masks[k * 256 + t] = (uint16_t)m;
}

// ---------------------------------------------------------------------------
// Pass 2: block = (bc, kgroup). Each thread owns one float4 output position,
// keeps its 16 u inputs in registers, loops 9 k's with masks from LDS.
// ---------------------------------------------------------------------------
__global__ __launch_bounds__(256) void pool_masked(const float4* __restrict__ u4,
                                                   const uint16_t* __restrict__ masks,
                                                   float4* __restrict__ out4) {
    __shared__ uint32_t lm[1152];   // 9 k * 256 masks * 2B = 4608 B
    const int bc = blockIdx.x >> 2;         // 0..255
    const int k0 = (blockIdx.x & 3) * 9;    // 0,9,18,27
    const int t = threadIdx.x;

    // cooperative mask staging (contiguous, uint32 loads)
    const uint32_t* mw = (const uint32_t*)(masks + k0 * 256);
    #pragma unroll
    for (int i = t; i < 1152; i += 256) lm[i] = mw[i];

    // u loads: 2 input rows x 8 cols, once per thread
    const int ub = bc * 1024 + (t >> 3) * 32 + (t & 7) * 2;  // float4 index
    float4 a0 = u4[ub];        // row 2*oh,   cols 0..3 of this 8-col slab
    float4 a1 = u4[ub + 1];    // row 2*oh,   cols 4..7
    float4 b0 = u4[ub + 16];   // row 2*oh+1, cols 0..3
    float4 b1 = u4[ub + 17];   // row 2*oh+1, cols 4..7

    __syncthreads();

    const uint16_t* lm16 = (const uint16_t*)lm;
    const int ob = (bc * NK + k0) * 256 + t;   // float4 index into output

    #pragma unroll
    for (int kk = 0; kk < 9; ++kk) {
        const unsigned m = lm16[kk * 256 + t];
        float4 o;
        o.x = (m & 0x0001u ? a0.x : 0.f) + (m & 0x0002u ? a0.y : 0.f)
            + (m & 0x0100u ? b0.x : 0.f) + (m & 0x0200u ? b0.y : 0.f);
        o.y = (m & 0x0004u ? a0.z : 0.f) + (m & 0x0008u ? a0.w : 0.f)
            + (m & 0x0400u ? b0.z : 0.f) + (m & 0x0800u ? b0.w : 0.f);
        o.z = (m & 0x0010u ? a1.x : 0.f) + (m & 0x0020u ? a1.y : 0.f)
            + (m & 0x1000u ? b1.x : 0.f) + (m & 0x2000u ? b1.y : 0.f);
        o.w = (m & 0x0040u ? a1.z : 0.f) + (m & 0x0080u ? a1.w : 0.f)
            + (m & 0x4000u ? b1.z : 0.f) + (m & 0x8000u ? b1.w : 0.f);
        out4[ob + kk * 256] = o;
    }
}

// ---------------------------------------------------------------------------
// Fallback (no workspace): direct compute, one float4 per thread.
// ---------------------------------------------------------------------------
__global__ __launch_bounds__(256) void pool_direct(const float4* __restrict__ u4,
                                                   const float4* __restrict__ rfs4,
                                                   float4* __restrict__ out4) {
    const int f = blockIdx.x * 256 + threadIdx.x;   // 0 .. 2359295
    const int t = f & 255;
    const int pk = f >> 8;          // bc*36 + k
    const int k = pk % NK;
    const int bc = pk / NK;
    const int ub = bc * 1024 + (t >> 3) * 32 + (t & 7) * 2;
    const int rb = k * 1024 + (t >> 3) * 32 + (t & 7) * 2;
    float4 a0 = u4[ub], a1 = u4[ub + 1], b0 = u4[ub + 16], b1 = u4[ub + 17];
    float4 r0 = rfs4[rb], r1 = rfs4[rb + 1], s0 = rfs4[rb + 16], s1 = rfs4[rb + 17];
    float4 o;
    o.x = a0.x * r0.x + a0.y * r0.y + b0.x * s0.x + b0.y * s0.y;
    o.y = a0.z * r0.z + a0.w * r0.w + b0.z * s0.z + b0.w * s0.w;
    o.z = a1.x * r1.x + a1.y * r1.y + b1.x * s1.x + b1.y * s1.y;
    o.w = a1.z * r1.z + a1.w * r1.w + b1.z * s1.z + b1.w * s1.w;
    out4[f] = o;
}

extern "C" void kernel_launch(void* const* d_in, const int* in_sizes, int n_in,
                              void* d_out, int out_size, void* d_ws, size_t ws_size,
                              hipStream_t stream) {
    const float* u = (const float*)d_in[0];     // (8,32,64,64)
    const float* rfs = (const float*)d_in[1];   // (36,64,64)
    float* out = (float*)d_out;                 // (8,32,36,32,32)

    if (ws_size >= (size_t)(NK * 256 * sizeof(uint16_t))) {
        uint16_t* masks = (uint16_t*)d_ws;
        pack_masks<<<NK, 256, 0, stream>>>((const float4*)rfs, masks);
        pool_masked<<<NB * NC * 4, 256, 0, stream>>>((const float4*)u, masks, (float4*)out);
    } else {
        pool_direct<<<(NB * NC * NK), 256, 0, stream>>>((const float4*)u, (const float4*)rfs,
                                                        (float4*)out);
    }
}

// Round 4
// 72.749 us; speedup vs baseline: 1.0234x; 1.0234x over previous
//
#include <hip/hip_runtime.h>
#include <stdint.h>

// Problem constants (fixed by setup_inputs)
#define NB 8
#define NC 32
#define NK 36
#define NH 64
#define NW 64
// Output: (8,32,36,32,32) fp32 = 36.9 MB. Memory-bound; write floor ~6 us.
// Single fused kernel: block = (bc-pair, kgroup-of-9). Each block:
//   1) packs 9 RF planes into 16-bit masks in LDS (rfs is L2/L3-resident),
//   2) loads 2 bc input slabs into registers (16 floats each),
//   3) 9-k inner loop: mask-select + add, coalesced float4 stores.
// thread t: oh = t>>3 (0..31), ow4 = t&7; pos covers input rows 2*oh,2*oh+1,
// cols 8*ow4..8*ow4+7.

__global__ __launch_bounds__(256) void pool_fused(const float4* __restrict__ u4,
                                                  const float4* __restrict__ rfs4,
                                                  float4* __restrict__ out4) {
    __shared__ uint16_t lm[9 * 256];   // 4.6 KB
    const int bid = blockIdx.x;        // 0..511
    const int kg = bid & 3;            // 0..3
    const int pair = bid >> 2;         // 0..127  (bc pair)
    const int k0 = kg * 9;
    const int t = threadIdx.x;
    const int pos = (t >> 3) * 32 + (t & 7) * 2;   // float4 index in a 64x64 plane

    // --- issue u loads early (overlap HBM latency with mask packing) ---
    const int bc0 = pair * 2;
    const int ub0 = bc0 * 1024 + pos;
    const int ub1 = ub0 + 1024;
    float4 a0 = u4[ub0], a1 = u4[ub0 + 1], b0 = u4[ub0 + 16], b1 = u4[ub0 + 17];
    float4 c0 = u4[ub1], c1 = u4[ub1 + 1], d0 = u4[ub1 + 16], d1 = u4[ub1 + 17];

    // --- pack this block's 9 RF planes into bitmasks (reads hit L2/L3) ---
    #pragma unroll
    for (int kk = 0; kk < 9; ++kk) {
        const int rb = (k0 + kk) * 1024 + pos;
        float4 r0a = rfs4[rb];        // row 2*oh,   cols 0..3 of 8-col slab
        float4 r0b = rfs4[rb + 1];    // row 2*oh,   cols 4..7
        float4 r1a = rfs4[rb + 16];   // row 2*oh+1, cols 0..3
        float4 r1b = rfs4[rb + 17];   // row 2*oh+1, cols 4..7
        unsigned m = 0;
        m |= (unsigned)(r0a.x > 0.5f) << 0;
        m |= (unsigned)(r0a.y > 0.5f) << 1;
        m |= (unsigned)(r0a.z > 0.5f) << 2;
        m |= (unsigned)(r0a.w > 0.5f) << 3;
        m |= (unsigned)(r0b.x > 0.5f) << 4;
        m |= (unsigned)(r0b.y > 0.5f) << 5;
        m |= (unsigned)(r0b.z > 0.5f) << 6;
        m |= (unsigned)(r0b.w > 0.5f) << 7;
        m |= (unsigned)(r1a.x > 0.5f) << 8;
        m |= (unsigned)(r1a.y > 0.5f) << 9;
        m |= (unsigned)(r1a.z > 0.5f) << 10;
        m |= (unsigned)(r1a.w > 0.5f) << 11;
        m |= (unsigned)(r1b.x > 0.5f) << 12;
        m |= (unsigned)(r1b.y > 0.5f) << 13;
        m |= (unsigned)(r1b.z > 0.5f) << 14;
        m |= (unsigned)(r1b.w > 0.5f) << 15;
        lm[kk * 256 + t] = (uint16_t)m;
    }

    __syncthreads();

    const int ob0 = (bc0 * NK + k0) * 256 + t;   // float4 index into output
    const int ob1 = ob0 + NK * 256;              // next bc plane

    #pragma unroll
    for (int kk = 0; kk < 9; ++kk) {
        const unsigned m = lm[kk * 256 + t];
        float4 o;
        o.x = (m & 0x0001u ? a0.x : 0.f) + (m & 0x0002u ? a0.y : 0.f)
            + (m & 0x0100u ? b0.x : 0.f) + (m & 0x0200u ? b0.y : 0.f);
        o.y = (m & 0x0004u ? a0.z : 0.f) + (m & 0x0008u ? a0.w : 0.f)
            + (m & 0x0400u ? b0.z : 0.f) + (m & 0x0800u ? b0.w : 0.f);
        o.z = (m & 0x0010u ? a1.x : 0.f) + (m & 0x0020u ? a1.y : 0.f)
            + (m & 0x1000u ? b1.x : 0.f) + (m & 0x2000u ? b1.y : 0.f);
        o.w = (m & 0x0040u ? a1.z : 0.f) + (m & 0x0080u ? a1.w : 0.f)
            + (m & 0x4000u ? b1.z : 0.f) + (m & 0x8000u ? b1.w : 0.f);
        out4[ob0 + kk * 256] = o;

        float4 p;
        p.x = (m & 0x0001u ? c0.x : 0.f) + (m & 0x0002u ? c0.y : 0.f)
            + (m & 0x0100u ? d0.x : 0.f) + (m & 0x0200u ? d0.y : 0.f);
        p.y = (m & 0x0004u ? c0.z : 0.f) + (m & 0x0008u ? c0.w : 0.f)
            + (m & 0x0400u ? d0.z : 0.f) + (m & 0x0800u ? d0.w : 0.f);
        p.z = (m & 0x0010u ? c1.x : 0.f) + (m & 0x0020u ? c1.y : 0.f)
            + (m & 0x1000u ? d1.x : 0.f) + (m & 0x2000u ? d1.y : 0.f);
        p.w = (m & 0x0040u ? c1.z : 0.f) + (m & 0x0080u ? c1.w : 0.f)
            + (m & 0x4000u ? d1.z : 0.f) + (m & 0x8000u ? d1.w : 0.f);
        out4[ob1 + kk * 256] = p;
    }
}

extern "C" void kernel_launch(void* const* d_in, const int* in_sizes, int n_in,
                              void* d_out, int out_size, void* d_ws, size_t ws_size,
                              hipStream_t stream) {
    const float* u = (const float*)d_in[0];     // (8,32,64,64)
    const float* rfs = (const float*)d_in[1];   // (36,64,64)
    float* out = (float*)d_out;                 // (8,32,36,32,32)

    // grid: 128 bc-pairs x 4 k-groups = 512 blocks, 256 threads (8 waves/CU at 2 blocks/CU)
    pool_fused<<<512, 256, 0, stream>>>((const float4*)u, (const float4*)rfs, (float4*)out);
}